// Round 11
// baseline (123.409 us; speedup 1.0000x reference)
//
#include <hip/hip_runtime.h>
#include <hip/hip_bf16.h>

// Problem constants (from reference)
constexpr int B = 16;
constexpr int N = 8192;
constexpr int H = 768;
constexpr int Q = 32;      // K_SEEDS
constexpr int K = 128;     // TOPK
#define SCALE 0.28867513459481287f   // 12^-0.5

typedef __attribute__((ext_vector_type(8))) short bf16x8_t;
typedef __attribute__((ext_vector_type(4))) float f32x4_t;

// LDS: xs[3 planes][128 n][128 B] (64 bf16/row) + ss[3][32 q][128 B]
#define XS_OFF 0
#define XS_PLANE 16384     // 128 rows * 128 B
#define SS_OFF 49152
#define SS_PLANE 4096      // 32 rows * 128 B
#define LDS_BYTES 61440

__device__ __forceinline__ float bf16_to_f32(ushort h) {
  return __uint_as_float(((uint32_t)h) << 16);
}
// hardware v_cvt bf16 cast (RNE on gfx950)
__device__ __forceinline__ ushort cvt_bf16(float f) {
  __hip_bfloat16 h = __float2bfloat16(f);
  return __builtin_bit_cast(unsigned short, h);
}
// f32 -> bf16 hi/mid/lo via HW cvt; residuals Sterbenz-exact.
// 3-split/6-pass REQUIRED: round 9 measured dropping the 2^-18 term families
// costs ~0.01 absmax each vs the 0.0108 threshold.
__device__ __forceinline__ void split3(float f, ushort& h, ushort& m, ushort& l) {
  h = cvt_bf16(f);
  float f1 = f - bf16_to_f32(h);
  m = cvt_bf16(f1);
  float f2 = f1 - bf16_to_f32(m);
  l = cvt_bf16(f2);
}

// 128B-row swizzle: XOR the 16B sub-block index (0..7) with row&7.
// Verified: b128 frag reads and b64 stage writes both land exactly at the
// bank-saturation minimum (no extra conflict cycles).
__device__ __forceinline__ int swz128(int row, int byte) {
  return row * 128 + ((((byte) >> 4) ^ (row & 7)) << 4) + (byte & 15);
}
__device__ __forceinline__ bf16x8_t ld_frag128(const char* p, int row, int byte) {
  return *reinterpret_cast<const bf16x8_t*>(p + swz128(row, byte));
}

#define MFMA(a, b, c) __builtin_amdgcn_mfma_f32_16x16x32_bf16(a, b, c, 0, 0, 0)

// Stage one row's 64-h segment (two float4 pairs) into 3 LDS planes.
#define STAGE_ROW(BASE, PLANE, ROW, F0, F1)                                    \
  {                                                                            \
    ushort4 uh0, um0, ul0, uh1, um1, ul1;                                      \
    split3((F0).x, uh0.x, um0.x, ul0.x);                                       \
    split3((F0).y, uh0.y, um0.y, ul0.y);                                       \
    split3((F0).z, uh0.z, um0.z, ul0.z);                                       \
    split3((F0).w, uh0.w, um0.w, ul0.w);                                       \
    split3((F1).x, uh1.x, um1.x, ul1.x);                                       \
    split3((F1).y, uh1.y, um1.y, ul1.y);                                       \
    split3((F1).z, uh1.z, um1.z, ul1.z);                                       \
    split3((F1).w, uh1.w, um1.w, ul1.w);                                       \
    char* d0 = (BASE) + swz128((ROW), byt0);                                   \
    char* d1 = (BASE) + swz128((ROW), byt1);                                   \
    *reinterpret_cast<ushort4*>(d0 + 0 * (PLANE)) = uh0;                       \
    *reinterpret_cast<ushort4*>(d0 + 1 * (PLANE)) = um0;                       \
    *reinterpret_cast<ushort4*>(d0 + 2 * (PLANE)) = ul0;                       \
    *reinterpret_cast<ushort4*>(d1 + 0 * (PLANE)) = uh1;                       \
    *reinterpret_cast<ushort4*>(d1 + 1 * (PLANE)) = um1;                       \
    *reinterpret_cast<ushort4*>(d1 + 2 * (PLANE)) = ul1;                       \
  }

// Stage one 64-h chunk: x (4 rows x 8 floats) + seed (1 row x 8 floats).
#define STAGE_CHUNK(PX0, PX1, PS0, PS1)                                        \
  {                                                                            \
    _Pragma("unroll") for (int r = 0; r < 4; ++r)                              \
        STAGE_ROW(lds + XS_OFF, XS_PLANE, sn + r * 32, PX0[r], PX1[r]);        \
    STAGE_ROW(lds + SS_OFF, SS_PLANE, sq, PS0, PS1);                           \
  }

// One 32-h half: 12 frag reads + 24 mfma (6 passes x 4 C-tiles)
#define MFMA_HALF(HB)                                                          \
  {                                                                            \
    const char* ssb = lds + SS_OFF;                                            \
    const char* xsb = lds + XS_OFF;                                            \
    const int ba = (HB) + l4 * 16;                                             \
    bf16x8_t a0H = ld_frag128(ssb + 0 * SS_PLANE, l15, ba);                    \
    bf16x8_t a1H = ld_frag128(ssb + 0 * SS_PLANE, 16 + l15, ba);               \
    bf16x8_t b0H = ld_frag128(xsb + 0 * XS_PLANE, nloc + l15, ba);             \
    bf16x8_t b1H = ld_frag128(xsb + 0 * XS_PLANE, nloc + 16 + l15, ba);        \
    bf16x8_t a0M = ld_frag128(ssb + 1 * SS_PLANE, l15, ba);                    \
    bf16x8_t a1M = ld_frag128(ssb + 1 * SS_PLANE, 16 + l15, ba);               \
    bf16x8_t b0M = ld_frag128(xsb + 1 * XS_PLANE, nloc + l15, ba);             \
    bf16x8_t b1M = ld_frag128(xsb + 1 * XS_PLANE, nloc + 16 + l15, ba);        \
    bf16x8_t a0L = ld_frag128(ssb + 2 * SS_PLANE, l15, ba);                    \
    bf16x8_t a1L = ld_frag128(ssb + 2 * SS_PLANE, 16 + l15, ba);               \
    bf16x8_t b0L = ld_frag128(xsb + 2 * XS_PLANE, nloc + l15, ba);             \
    bf16x8_t b1L = ld_frag128(xsb + 2 * XS_PLANE, nloc + 16 + l15, ba);        \
    acc00 = MFMA(a0H, b0H, acc00); acc01 = MFMA(a0H, b1H, acc01);              \
    acc10 = MFMA(a1H, b0H, acc10); acc11 = MFMA(a1H, b1H, acc11);              \
    acc00 = MFMA(a0H, b0M, acc00); acc01 = MFMA(a0H, b1M, acc01);              \
    acc10 = MFMA(a1H, b0M, acc10); acc11 = MFMA(a1H, b1M, acc11);              \
    acc00 = MFMA(a0M, b0H, acc00); acc01 = MFMA(a0M, b1H, acc01);              \
    acc10 = MFMA(a1M, b0H, acc10); acc11 = MFMA(a1M, b1H, acc11);              \
    acc00 = MFMA(a0M, b0M, acc00); acc01 = MFMA(a0M, b1M, acc01);              \
    acc10 = MFMA(a1M, b0M, acc10); acc11 = MFMA(a1M, b1M, acc11);              \
    acc00 = MFMA(a0H, b0L, acc00); acc01 = MFMA(a0H, b1L, acc01);              \
    acc10 = MFMA(a1H, b0L, acc10); acc11 = MFMA(a1H, b1L, acc11);              \
    acc00 = MFMA(a0L, b0H, acc00); acc01 = MFMA(a0L, b1H, acc01);              \
    acc10 = MFMA(a1L, b0H, acc10); acc11 = MFMA(a1L, b1H, acc11);              \
  }
#define MFMA_CHUNK() { MFMA_HALF(0); MFMA_HALF(64); }

// ---------------------------------------------------------------------------
// Kernel 1 (MFMA bf16x3, 64-h chunks): scores[b*Q+q][n] = dot(x[b,n,:],
// seed[q,:]). Grid 1024 blocks x 256 threads; block = (b=bid>>6, nb=bid&63),
// 128 n-rows, all 32 q; 12 chunks of 64 h (256 B contiguous per row per
// chunk for DRAM streaming efficiency); 2 blocks/CU.
// ---------------------------------------------------------------------------
__global__ __launch_bounds__(256, 2) void k_scores(const float* __restrict__ x,
                                                   const float* __restrict__ seed,
                                                   float* __restrict__ scores) {
  __shared__ __align__(16) char lds[LDS_BYTES];

  const int tid = threadIdx.x;
  const int bid = blockIdx.x;
  const int b = bid >> 6;
  const int nb = bid & 63;
  const size_t xbase = ((size_t)b * N + (size_t)nb * 128) * H;

  const int lane = tid & 63;
  const int wave = tid >> 6;           // 0..3
  const int l15 = lane & 15;
  const int l4 = lane >> 4;
  const int nloc = wave * 32;

  // staging indices: thread covers rows sn + r*32 (x) / sq (seed),
  // float cols [sh, sh+4) and [sh+32, sh+36) within the 64-h chunk.
  const int sn = tid >> 3;             // 0..31
  const int sq = tid >> 3;             // 0..31
  const int sh = (tid & 7) << 2;       // 0,4,...,28
  const int byt0 = (tid & 7) << 3;     // byte col of seg0 (bf16)
  const int byt1 = byt0 + 64;          // byte col of seg1

  f32x4_t acc00 = {0.f, 0.f, 0.f, 0.f};
  f32x4_t acc01 = {0.f, 0.f, 0.f, 0.f};
  f32x4_t acc10 = {0.f, 0.f, 0.f, 0.f};
  f32x4_t acc11 = {0.f, 0.f, 0.f, 0.f};

  float4 pxA0[4], pxA1[4], pxB0[4], pxB1[4];
  float4 psA0, psA1, psB0, psB1;

  const float* xp = x + xbase + sh;
  const float* sp = seed + (size_t)sq * H + sh;

  // prologue: chunk 0 -> A regs
  {
#pragma unroll
    for (int r = 0; r < 4; ++r) {
      const float* p = xp + (size_t)(sn + r * 32) * H;
      pxA0[r] = *reinterpret_cast<const float4*>(p);
      pxA1[r] = *reinterpret_cast<const float4*>(p + 32);
    }
    psA0 = *reinterpret_cast<const float4*>(sp);
    psA1 = *reinterpret_cast<const float4*>(sp + 32);
  }

#pragma unroll 1
  for (int c = 0; c < 12; c += 2) {
    // prefetch chunk c+1 -> B regs (issue before consuming A)
    {
      const int o = (c + 1) * 64;
#pragma unroll
      for (int r = 0; r < 4; ++r) {
        const float* p = xp + (size_t)(sn + r * 32) * H + o;
        pxB0[r] = *reinterpret_cast<const float4*>(p);
        pxB1[r] = *reinterpret_cast<const float4*>(p + 32);
      }
      psB0 = *reinterpret_cast<const float4*>(sp + o);
      psB1 = *reinterpret_cast<const float4*>(sp + o + 32);
    }
    STAGE_CHUNK(pxA0, pxA1, psA0, psA1);
    __syncthreads();
    MFMA_CHUNK();
    __syncthreads();

    // prefetch chunk c+2 -> A regs
    if (c + 2 < 12) {
      const int o = (c + 2) * 64;
#pragma unroll
      for (int r = 0; r < 4; ++r) {
        const float* p = xp + (size_t)(sn + r * 32) * H + o;
        pxA0[r] = *reinterpret_cast<const float4*>(p);
        pxA1[r] = *reinterpret_cast<const float4*>(p + 32);
      }
      psA0 = *reinterpret_cast<const float4*>(sp + o);
      psA1 = *reinterpret_cast<const float4*>(sp + o + 32);
    }
    STAGE_CHUNK(pxB0, pxB1, psB0, psB1);
    __syncthreads();
    MFMA_CHUNK();
    __syncthreads();
  }

  // epilogue: C[q][n]: q = qt*16 + l4*4 + r, n = nb*128 + nloc + nt*16 + l15
  float* srow = scores + (((size_t)(b * Q)) << 13) + nb * 128 + nloc;
#pragma unroll
  for (int r = 0; r < 4; ++r) {
    srow[((size_t)(l4 * 4 + r) << 13) + l15] = acc00[r];
    srow[((size_t)(l4 * 4 + r) << 13) + 16 + l15] = acc01[r];
    srow[((size_t)(16 + l4 * 4 + r) << 13) + l15] = acc10[r];
    srow[((size_t)(16 + l4 * 4 + r) << 13) + 16 + l15] = acc11[r];
  }
}

// ---------------------------------------------------------------------------
// Kernel 2 (unchanged): per (b,q) row: top-128 -> softmax -> gather V.
// Grid 512 blocks x 512 threads.
// ---------------------------------------------------------------------------
__global__ __launch_bounds__(512) void k_topk(const float* __restrict__ scores,
                                              const float* __restrict__ x,
                                              float* __restrict__ out) {
  const int bq = blockIdx.x;
  const int b = bq >> 5;
  const int tid = threadIdx.x;
  const float* srow = scores + ((size_t)bq << 13);

  // Load 16 scores per thread; build monotonic uint keys.
  float f[16];
  uint32_t u[16];
  const float4* s4 = reinterpret_cast<const float4*>(srow);
#pragma unroll
  for (int i = 0; i < 4; ++i) {
    float4 v = s4[i * 512 + tid];
    f[i * 4 + 0] = v.x; f[i * 4 + 1] = v.y;
    f[i * 4 + 2] = v.z; f[i * 4 + 3] = v.w;
  }
#pragma unroll
  for (int e = 0; e < 16; ++e) {
    uint32_t bits = __float_as_uint(f[e]);
    u[e] = (bits & 0x80000000u) ? ~bits : (bits | 0x80000000u);
  }

  // Binary search smallest T with count(u > T) < K.
  __shared__ int s_red[8];
  uint32_t lo = 0u, hi = 0xFFFFFFFFu;
  while (lo < hi) {
    uint32_t mid = lo + ((hi - lo) >> 1);
    int cnt = 0;
#pragma unroll
    for (int e = 0; e < 16; ++e) cnt += (u[e] > mid) ? 1 : 0;
#pragma unroll
    for (int m = 1; m < 64; m <<= 1) cnt += __shfl_xor(cnt, m);
    if ((tid & 63) == 0) s_red[tid >> 6] = cnt;
    __syncthreads();
    cnt = 0;
#pragma unroll
    for (int w = 0; w < 8; ++w) cnt += s_red[w];
    if (cnt >= K) lo = mid + 1; else hi = mid;
    __syncthreads();
  }
  const uint32_t T = lo;

  // Collect strictly-greater, then lowest-index ties == T.
  __shared__ int s_cnt, s_eqn;
  __shared__ int s_idx[K];
  __shared__ float s_w[K];
  __shared__ int s_eq[256];
  __shared__ float s_m, s_sum;
  if (tid == 0) { s_cnt = 0; s_eqn = 0; }
  __syncthreads();
#pragma unroll
  for (int e = 0; e < 16; ++e) {
    int n = (((e >> 2) * 512 + tid) << 2) + (e & 3);
    if (u[e] > T) {
      int p = atomicAdd(&s_cnt, 1);
      s_idx[p] = n;
      s_w[p] = f[e];
    } else if (u[e] == T) {
      int p = atomicAdd(&s_eqn, 1);
      if (p < 256) s_eq[p] = n;
    }
  }
  __syncthreads();
  const int c1 = s_cnt;
  const int need = K - c1;
  if (tid == 0 && need > 0) {
    uint32_t tb = (T & 0x80000000u) ? (T ^ 0x80000000u) : ~T;
    float tf = __uint_as_float(tb);
    int m = s_eqn; if (m > 256) m = 256;
    for (int a = 0; a < need; ++a) {       // selection-sort lowest indices
      int best = s_eq[a], bi = a;
      for (int z = a + 1; z < m; ++z)
        if (s_eq[z] < best) { best = s_eq[z]; bi = z; }
      s_eq[bi] = s_eq[a]; s_eq[a] = best;
      s_idx[c1 + a] = best;
      s_w[c1 + a] = tf;
    }
  }
  __syncthreads();

  // Softmax over the 128 selected values (store un-normalized exp in s_w).
  if (tid < 64) {
    float v = fmaxf(s_w[tid], s_w[tid + 64]);
#pragma unroll
    for (int m = 1; m < 64; m <<= 1) v = fmaxf(v, __shfl_xor(v, m));
    if (tid == 0) s_m = v;
  }
  __syncthreads();
  const float mx = s_m * SCALE;
  if (tid < K) s_w[tid] = __expf(s_w[tid] * SCALE - mx);
  __syncthreads();
  if (tid < 64) {
    float v = s_w[tid] + s_w[tid + 64];
#pragma unroll
    for (int m = 1; m < 64; m <<= 1) v += __shfl_xor(v, m);
    if (tid == 0) s_sum = v;
  }
  __syncthreads();

  // Gather + weighted sum: 2 k-slices x 192 threads x float4 (768 floats).
  __shared__ __align__(16) float s_part[H];   // 3 KiB
  {
    const int t = tid & 255;        // lane within slice
    const int ks = tid >> 8;        // k-slice: 0 or 1
    float4 acc = make_float4(0.f, 0.f, 0.f, 0.f);
    if (t < 192) {
      const float4* xb =
          reinterpret_cast<const float4*>(x + (((size_t)b) << 13) * H);
      const int k0 = ks << 6;
#pragma unroll 4
      for (int k = k0; k < k0 + 64; ++k) {
        const float w = s_w[k];
        const float4 v = xb[(size_t)s_idx[k] * (H / 4) + t];
        acc.x = fmaf(w, v.x, acc.x);
        acc.y = fmaf(w, v.y, acc.y);
        acc.z = fmaf(w, v.z, acc.z);
        acc.w = fmaf(w, v.w, acc.w);
      }
    }
    if (ks == 0 && t < 192)
      reinterpret_cast<float4*>(s_part)[t] = acc;
    __syncthreads();
    if (ks == 1 && t < 192) {
      const float4 p = reinterpret_cast<const float4*>(s_part)[t];
      const float inv = 1.f / s_sum;
      float4 o;
      o.x = (acc.x + p.x) * inv;
      o.y = (acc.y + p.y) * inv;
      o.z = (acc.z + p.z) * inv;
      o.w = (acc.w + p.w) * inv;
      reinterpret_cast<float4*>(out)[(size_t)bq * (H / 4) + t] = o;
    }
  }
}

extern "C" void kernel_launch(void* const* d_in, const int* in_sizes, int n_in,
                              void* d_out, int out_size, void* d_ws, size_t ws_size,
                              hipStream_t stream) {
  const float* x = (const float*)d_in[0];     // [B, N, H] f32
  const float* seed = (const float*)d_in[1];  // [1, Q, H] f32
  float* out = (float*)d_out;                 // [B, Q, H] f32
  float* scores = (float*)d_ws;               // [B*Q, N] f32 = 16 MiB scratch

  k_scores<<<1024, 256, 0, stream>>>(x, seed, scores);
  k_topk<<<512, 512, 0, stream>>>(scores, x, out);
}